// Round 1
// 472.597 us; speedup vs baseline: 1.0554x; 1.0554x over previous
//
#include <hip/hip_runtime.h>
#include <math.h>

#define L_DIM 8
#define T_DIM 128
#define S_DIM 128
#define SP1   129
#define BIGF  1000000000.0f
#define EPSF  1e-5f
#define NTHREADS 1024
#define NWAVES 16
#define QK_FLOATS (2 * S_DIM * SP1)   // q+k incl. bias col: 33024 floats = 129 KiB
#define QK_CHUNKS 129                 // 1 KiB wave-chunks (64 lanes x 16 B)

// ---- DPP cross-lane reductions on the VALU pipe ----
template<int CTRL>
__device__ __forceinline__ float dpp_add_part(float x) {
    int r = __builtin_amdgcn_update_dpp(0, __float_as_int(x), CTRL, 0xF, 0xF, false);
    return __int_as_float(r);
}
template<int CTRL>
__device__ __forceinline__ float dpp_self(float x) {
    int r = __builtin_amdgcn_update_dpp(__float_as_int(x), __float_as_int(x), CTRL, 0xF, 0xF, false);
    return __int_as_float(r);
}
// Sum over 64 lanes; total lands in lane 63.
__device__ __forceinline__ float dppSum63(float x) {
    x += dpp_add_part<0x111>(x);  // row_shr:1
    x += dpp_add_part<0x112>(x);  // row_shr:2
    x += dpp_add_part<0x114>(x);  // row_shr:4
    x += dpp_add_part<0x118>(x);  // row_shr:8
    x += dpp_add_part<0x142>(x);  // row_bcast:15
    x += dpp_add_part<0x143>(x);  // row_bcast:31
    return x;
}
// Max over 64 lanes; total lands in lane 63.
__device__ __forceinline__ float dppMax63(float x) {
    x = fmaxf(x, dpp_self<0x111>(x));
    x = fmaxf(x, dpp_self<0x112>(x));
    x = fmaxf(x, dpp_self<0x114>(x));
    x = fmaxf(x, dpp_self<0x118>(x));
    x = fmaxf(x, dpp_self<0x142>(x));
    x = fmaxf(x, dpp_self<0x143>(x));
    return x;
}
__device__ __forceinline__ float lane63(float x) {
    return __int_as_float(__builtin_amdgcn_readlane(__float_as_int(x), 63));
}

// ---- raw barriers: s_barrier WITHOUT the vmcnt(0) drain __syncthreads emits.
//      This is what lets cross-layer prefetch loads stay in flight across the
//      serial chain (AITER/HK counted-waitcnt discipline). lgkmcnt(0) before
//      the barrier orders LDS writes; memory clobbers pin code motion. ----
__device__ __forceinline__ void wg_bar() {
    asm volatile("s_waitcnt lgkmcnt(0)" ::: "memory");
    __builtin_amdgcn_s_barrier();
    asm volatile("" ::: "memory");
}
// The ONE vmcnt drain per layer: right before consuming the staged q,k tile.
__device__ __forceinline__ void wg_bar_vm() {
    asm volatile("s_waitcnt vmcnt(0) lgkmcnt(0)" ::: "memory");
    __builtin_amdgcn_s_barrier();
    asm volatile("" ::: "memory");
}

// async global->LDS, 16B per lane (global_load_lds_dwordx4)
__device__ __forceinline__ void gld_lds16(const float* g, float* l) {
    __builtin_amdgcn_global_load_lds(
        (const __attribute__((address_space(1))) void*)g,
        (__attribute__((address_space(3))) void*)l,
        16, 0, 0);
}

// Stage q,k of one attn_n[b][t] (flat 129 KiB) into LDS. Waves 2..15 only, so
// the mailbox-polling waves (0,1) never force-drain the staging stream.
__device__ __forceinline__ void stage_qk(const float* __restrict__ src,
                                         float* __restrict__ lds, int wid, int lane) {
    if (wid >= 2) {
#pragma unroll
        for (int k = 0; k < 10; ++k) {
            int c = (wid - 2) + k * 14;         // 129 chunks over 14 waves
            if (c < QK_CHUNKS) {
                gld_lds16(src + c * 256 + lane * 4, lds + c * 256);
            }
        }
    }
}

// t-attention weight rows: register prefetch (8 rows/thread, it-pipelined)
struct TR { float lo[8], hi[8], b[8]; };
__device__ __forceinline__ void t_load(const float* __restrict__ m, int lane, int wid, TR& R) {
#pragma unroll
    for (int u = 0; u < 8; ++u) {
        const float* row = m + (size_t)(wid + u * NWAVES) * SP1;
        R.lo[u] = row[lane];
        R.hi[u] = row[lane + 64];
        R.b[u]  = row[128];
    }
}
__device__ __forceinline__ void t_compute(const TR& R, float v0, float v1,
                                          int lane, int wid, float* __restrict__ dst) {
    float acc[8];
#pragma unroll
    for (int u = 0; u < 8; ++u) acc[u] = R.lo[u] * v0 + R.hi[u] * v1;
#pragma unroll
    for (int u = 0; u < 8; ++u) acc[u] = dppSum63(acc[u]);
    if (lane == 63) {
#pragma unroll
        for (int u = 0; u < 8; ++u) dst[wid + u * NWAVES] = acc[u] + R.b[u];
    }
}

// v-matrix of attn_n[b][t]: register prefetch (24 VGPRs/thread)
__device__ __forceinline__ void v_load(const float* __restrict__ vb, int lane, int wid,
                                       float vlo[8], float vhi[8], float vbi[8]) {
#pragma unroll
    for (int u = 0; u < 8; ++u) {
        const float* row = vb + (size_t)(wid + u * NWAVES) * SP1;
        vlo[u] = row[lane];
        vhi[u] = row[lane + 64];
        vbi[u] = row[128];
    }
}

// n-attention qkv consume: q,k from staged LDS (conflict-free: lanes read
// consecutive dwords; compiler merges lane/lane+64 into ds_read2_b32), v from regs.
__device__ __forceinline__ void nqkv_consume(const float* __restrict__ st,
                                             const float vlo[8], const float vhi[8], const float vbi[8],
                                             float tv0, float tv1, int lane, int wid,
                                             float* __restrict__ lds_q,
                                             float* __restrict__ lds_k,
                                             float* __restrict__ lds_v)
{
#pragma unroll
    for (int it = 0; it < 2; ++it) {
        float* dst = (it == 0) ? lds_q : lds_k;
        const float* m = st + it * S_DIM * SP1;
        float acc[8], bias[8];
#pragma unroll
        for (int u = 0; u < 8; ++u) {
            int base = (wid + u * NWAVES) * SP1;
            float lo = m[base + lane];
            float hi = m[base + lane + 64];
            bias[u]  = m[base + 128];          // broadcast read
            acc[u] = lo * tv0 + hi * tv1;
        }
#pragma unroll
        for (int u = 0; u < 8; ++u) acc[u] = dppSum63(acc[u]);
        if (lane == 63) {
#pragma unroll
            for (int u = 0; u < 8; ++u) dst[wid + u * NWAVES] = acc[u] + bias[u];
        }
    }
    {
        float acc[8];
#pragma unroll
        for (int u = 0; u < 8; ++u) acc[u] = vlo[u] * tv0 + vhi[u] * tv1;
#pragma unroll
        for (int u = 0; u < 8; ++u) acc[u] = dppSum63(acc[u]);
        if (lane == 63) {
#pragma unroll
            for (int u = 0; u < 8; ++u) lds_v[wid + u * NWAVES] = acc[u] + vbi[u];
        }
    }
}

// 128-row attention softmax + @v + residual (unchanged numerics)
template <bool MASKED>
__device__ __forceinline__ void attn_softmax(int lane, int wid,
                                             const float* __restrict__ lds_q,
                                             const float* __restrict__ lds_k,
                                             const float* __restrict__ lds_v,
                                             const float* __restrict__ lds_m,
                                             const float* __restrict__ resid,
                                             float* __restrict__ lds_out)
{
    const float scale = 0.08838834764831845f; // rsqrt(128)
    float k0 = lds_k[lane], k1 = lds_k[lane + 64];
    float v0 = lds_v[lane], v1 = lds_v[lane + 64];
    float m0 = 0.0f, m1 = 0.0f;
    if (MASKED) { m0 = lds_m[lane]; m1 = lds_m[lane + 64]; }

    float s1[8], s2[8], mx[8];
#pragma unroll
    for (int u = 0; u < 8; ++u) {
        int r = wid + u * NWAVES;
        float q = lds_q[r];
        float a1v = 0.0f, a2v = 0.0f;
        if (MASKED) {
            float mr = lds_m[r];
            a1v = BIGF * (1.0f - mr * m0);
            a2v = BIGF * (1.0f - mr * m1);
        }
        s1[u] = q * k0 * scale - a1v;
        s2[u] = q * k1 * scale - a2v;
    }
#pragma unroll
    for (int u = 0; u < 8; ++u) mx[u] = lane63(dppMax63(fmaxf(s1[u], s2[u])));
    float den[8], num[8];
#pragma unroll
    for (int u = 0; u < 8; ++u) {
        float e1 = __expf(s1[u] - mx[u]);
        float e2 = __expf(s2[u] - mx[u]);
        den[u] = e1 + e2;
        num[u] = e1 * v0 + e2 * v1;
    }
#pragma unroll
    for (int u = 0; u < 8; ++u) { den[u] = dppSum63(den[u]); num[u] = dppSum63(num[u]); }
    if (lane == 63) {
#pragma unroll
        for (int u = 0; u < 8; ++u) {
            int r = wid + u * NWAVES;
            lds_out[r] = num[u] / den[u] + resid[r];
        }
    }
}

__global__ __launch_bounds__(NTHREADS)
void net_kernel(const float* __restrict__ x,
                const float* __restrict__ W,
                const float* __restrict__ maskp,
                const float* __restrict__ attn_t,
                const float* __restrict__ attn_n,
                const float* __restrict__ norm_params,
                const float* __restrict__ ada,
                float* __restrict__ out,
                unsigned long long* __restrict__ mbox)
{
    const int t    = blockIdx.x;
    const int tid  = threadIdx.x;
    const int lane = tid & 63;
    const int wid  = tid >> 6;

    __shared__ float lds_stage[QK_FLOATS];  // staged q,k of attn_n[b][t] (129 KiB)
    __shared__ float lds_vals[S_DIM];
    __shared__ float lds_q[S_DIM], lds_k[S_DIM], lds_v[S_DIM];
    __shared__ float lds_tv[S_DIM];
    __shared__ float lds_vn[S_DIM];
    __shared__ float lds_m[S_DIM];
    __shared__ float lds_rs[2], lds_rq[2];  // LN partials (waves 0,1 only)
    __shared__ float lds_ra[2][2];          // aff partials, layer-parity slots

    TR Ra;                                  // next t-attn it0 rows
    float vlo[8], vhi[8], vbi[8];           // next n-attn v rows

    // ---- prologue: prefetch everything layer 0 needs ----
    {
        const float* src0 = attn_n + (size_t)t * 3 * S_DIM * SP1;
        t_load(attn_t, lane, wid, Ra);                    // oldest in flight
        stage_qk(src0, lds_stage, wid, lane);
        v_load(src0 + 2 * S_DIM * SP1, lane, wid, vlo, vhi, vbi);
    }

    for (int b = 0; b < L_DIM; ++b) {
        // per-layer aux: issue early, use late
        float m_r = 0.f, np0 = 0.f, np1 = 0.f, a0 = 0.f, a1 = 0.f, wreg = 0.f;
        if (tid < S_DIM) {
            m_r  = maskp[(size_t)(b * T_DIM + t) * S_DIM + tid];
            np0  = norm_params[(b * 2 + 0) * S_DIM + tid];
            np1  = norm_params[(b * 2 + 1) * S_DIM + tid];
            wreg = W[(size_t)(b * T_DIM + t) * SP1 + tid];
            lds_m[tid] = m_r;
            if (b > 0) {
                a0 = ada[((b - 1) * T_DIM + tid) * 2 + 0];
                a1 = ada[((b - 1) * T_DIM + tid) * 2 + 1];
            }
        }
        float wbias = (tid == 0) ? W[(size_t)(b * T_DIM + t) * SP1 + 128] : 0.f;

        // ---- 1. prev outputs via relaxed-atomic mailbox + gelu(ada) ----
        float v = 0.f;
        if (tid < S_DIM) {
            if (b == 0) {
                v = x[tid];
            } else {
                const unsigned long long* mb = mbox + (size_t)(b - 1) * T_DIM;
                unsigned long long w;
                do {
                    w = __hip_atomic_load(&mb[tid], __ATOMIC_RELAXED, __HIP_MEMORY_SCOPE_AGENT);
                } while ((unsigned int)(w >> 32) != (unsigned int)b);
                float raw = __uint_as_float((unsigned int)w);
                float z  = raw * a0;
                float z3 = z * z * z;
                float g  = 0.5f * z * (1.0f + tanhf(0.7978845608028654f * (z + 0.044715f * z3)));
                v = g * a1;
            }
            float s = dppSum63(v);
            if (lane == 63) lds_rs[wid] = s;
        }
        wg_bar(); // B1: LN sum partials visible
        float mu = (lds_rs[0] + lds_rs[1]) * (1.0f / 128.0f);
        {
            float d  = (tid < S_DIM) ? (v - mu) : 0.f;
            float s2 = dppSum63(d * d);
            if (lane == 63 && wid < 2) lds_rq[wid] = s2;
        }
        wg_bar(); // B1b: LN var partials visible
        if (tid < S_DIM) {
            float var  = (lds_rq[0] + lds_rq[1]) * (1.0f / 128.0f);
            float rstd = rsqrtf(var + EPSF);
            lds_vals[tid] = (v - mu) * rstd * np0 + np1;
        }
        wg_bar(); // B2: normalized vals visible

        // ---- 3. t-attention qkv (it0 prefetched last layer; pipeline it1/it2) ----
        {
            float vin0 = lds_vals[lane], vin1 = lds_vals[lane + 64];
            const float* bb = attn_t + (size_t)b * 3 * S_DIM * SP1;
            TR Rb;
            t_load(bb + 1 * S_DIM * SP1, lane, wid, Rb);
            t_compute(Ra, vin0, vin1, lane, wid, lds_q);
            t_load(bb + 2 * S_DIM * SP1, lane, wid, Ra);
            t_compute(Rb, vin0, vin1, lane, wid, lds_k);
            t_compute(Ra, vin0, vin1, lane, wid, lds_v);
        }
        wg_bar(); // B3

        // ---- 4. t-attention softmax (no mask) + residual ----
        attn_softmax<false>(lane, wid, lds_q, lds_k, lds_v, lds_m, lds_vals, lds_tv);
        wg_bar_vm(); // B4: the one vmcnt drain — staged q,k for layer b now visible

        // ---- 5. n-attention qkv: q,k from LDS stage, v from regs ----
        {
            float tv0 = lds_tv[lane], tv1 = lds_tv[lane + 64];
            nqkv_consume(lds_stage, vlo, vhi, vbi, tv0, tv1, lane, wid, lds_q, lds_k, lds_v);
        }
        wg_bar(); // B5: n-qkv results visible; lds_stage free for overwrite

        // ---- 6. n-attention softmax (mask recomputed on the fly) ----
        attn_softmax<true>(lane, wid, lds_q, lds_k, lds_v, lds_m, lds_tv, lds_vn);
        wg_bar(); // B6

        // ---- prefetch layer b+1 (stays in flight across aff/publish/poll/LN/t-attn) ----
        if (b < L_DIM - 1) {
            const float* srcn = attn_n + (size_t)((b + 1) * T_DIM + t) * 3 * S_DIM * SP1;
            t_load(attn_t + (size_t)(b + 1) * 3 * S_DIM * SP1, lane, wid, Ra); // oldest first
            stage_qk(srcn, lds_stage, wid, lane);
            v_load(srcn + 2 * S_DIM * SP1, lane, wid, vlo, vhi, vbi);
        }

        // ---- 7. aff = sum_s W*mask*vals_n + bias; publish via mailbox ----
        {
            float term = (tid < S_DIM) ? (wreg * m_r * lds_vn[tid]) : 0.f;
            float sa = dppSum63(term);
            if (lane == 63 && wid < 2) lds_ra[b & 1][wid] = sa;
        }
        wg_bar(); // B7
        if (tid == 0) {
            float aff = wbias + lds_ra[b & 1][0] + lds_ra[b & 1][1];
            if (b == L_DIM - 1) {
                out[t] = aff;
            } else {
                unsigned long long w =
                    ((unsigned long long)(unsigned int)(b + 1) << 32) |
                    (unsigned long long)__float_as_uint(aff);
                __hip_atomic_store(&mbox[(size_t)b * T_DIM + t], w,
                                   __ATOMIC_RELAXED, __HIP_MEMORY_SCOPE_AGENT);
            }
        }
        // no trailing barrier needed: lds_ra uses layer-parity slots, and every
        // buffer written early next layer had its last reader >=1 barrier back.
    }
}

extern "C" void kernel_launch(void* const* d_in, const int* in_sizes, int n_in,
                              void* d_out, int out_size, void* d_ws, size_t ws_size,
                              hipStream_t stream) {
    const float* x           = (const float*)d_in[0];
    const float* W           = (const float*)d_in[1];
    const float* maskp       = (const float*)d_in[2];
    const float* attn_t      = (const float*)d_in[3];
    const float* attn_n      = (const float*)d_in[4];
    // d_in[5] = attn_mask_n (67 MB) intentionally unused: recomputed from mask
    const float* norm_params = (const float*)d_in[6];
    const float* ada         = (const float*)d_in[7];
    float* out = (float*)d_out;

    unsigned long long* mbox = (unsigned long long*)d_ws; // 7 epochs x 128 slots x 8B

    hipMemsetAsync(d_ws, 0, (size_t)(L_DIM - 1) * T_DIM * sizeof(unsigned long long), stream);

    void* args[] = { (void*)&x, (void*)&W, (void*)&maskp, (void*)&attn_t, (void*)&attn_n,
                     (void*)&norm_params, (void*)&ada, (void*)&out, (void*)&mbox };
    hipLaunchCooperativeKernel((const void*)net_kernel, dim3(T_DIM), dim3(NTHREADS),
                               args, 0, stream);
}